// Round 4
// baseline (2043.134 us; speedup 1.0000x reference)
//
#include <hip/hip_runtime.h>
#include <hip/hip_bf16.h>

#define NN 100000      // nodes
#define NE 1000000     // edges
#define D  128         // hidden / input dim
#define NC 16          // classes

typedef short short8 __attribute__((ext_vector_type(8)));
typedef float f32x4  __attribute__((ext_vector_type(4)));

__device__ __forceinline__ float bf2f(ushort u) {
  union { unsigned int i; float f; } v; v.i = ((unsigned int)u) << 16; return v.f;
}
__device__ __forceinline__ ushort f2bf(float f) {
  union { float f; unsigned int i; } v; v.f = f;
  unsigned int x = v.i;
  return (ushort)((x + 0x7FFFu + ((x >> 16) & 1u)) >> 16);  // RNE
}

// ---- sniff dtypes: flags[0]=1 if float tensors are f32; flags[1]=1 if idx int64
__global__ void sniff_k(const ushort* __restrict__ xr, const unsigned int* __restrict__ ei,
                        int* __restrict__ flags) {
  if (threadIdx.x != 0 || blockIdx.x != 0) return;
  // x ~ N(0,1), no zeros. bf16 data: all 16b words have exponent near 127.
  // f32 data: every even (low-mantissa) word is uniform bits -> insane exponents.
  int f32 = 0;
  for (int i = 0; i < 128; ++i) {
    unsigned int e = ((unsigned int)xr[i] >> 7) & 0xFFu;
    if (e < 97u || e > 157u) f32 = 1;
  }
  flags[0] = f32;
  unsigned int s = 0;
  for (int i = 1; i < 256; i += 2) s |= ei[i];   // int64 < 2^31 => hi words all 0
  flags[1] = (s == 0) ? 1 : 0;
}

// ---- materialize clean int32 indices, clamped to [0,NN) ---------------------
__global__ void convert_idx_k(const int* __restrict__ ei, const int* __restrict__ flags,
                              int* __restrict__ idx, int n) {
  int i = blockIdx.x * blockDim.x + threadIdx.x;
  if (i >= n) return;
  int v = flags[1] ? ei[2 * i] : ei[i];   // int64: take low word
  v = v < 0 ? 0 : (v >= NN ? NN - 1 : v);
  idx[i] = v;
}

// ---- convert x to canonical bf16 -------------------------------------------
__global__ void convert_x_k(const void* __restrict__ xin, const int* __restrict__ flags,
                            ushort* __restrict__ xb) {
  int i = blockIdx.x * blockDim.x + threadIdx.x;
  const int n4 = NN * D / 4;
  if (i >= n4) return;
  ushort4 o;
  if (flags[0]) {
    float4 v = ((const float4*)xin)[i];
    o.x = f2bf(v.x); o.y = f2bf(v.y); o.z = f2bf(v.z); o.w = f2bf(v.w);
  } else {
    o = ((const ushort4*)xin)[i];
  }
  ((ushort4*)xb)[i] = o;
}

// ---- convert all weights/biases to canonical bf16 block --------------------
struct WPtrs { const void* p[10]; };
#define WTOT 102800
__global__ void convert_w_k(WPtrs w, const int* __restrict__ flags, ushort* __restrict__ wb) {
  const int off[10] = {0, 16384, 32768, 49152, 65536, 98304, 102400, 102528, 102656, 102784};
  int i = blockIdx.x * blockDim.x + threadIdx.x;
  if (i >= WTOT) return;
  int seg = 0;
  #pragma unroll
  for (int s2 = 1; s2 < 10; ++s2) if (i >= off[s2]) seg = s2;
  int j = i - off[seg];
  wb[i] = flags[0] ? f2bf(((const float*)w.p[seg])[j]) : ((const ushort*)w.p[seg])[j];
}

// ---- degree count (dst is layer-invariant: run once) -----------------------
__global__ void count_k(const int* __restrict__ dst, int* __restrict__ cnt, int E) {
  int e = blockIdx.x * blockDim.x + threadIdx.x;
  if (e < E) atomicAdd(&cnt[dst[e]], 1);
}

// ---- scatter-add x[src][koff..koff+63] into f32 agg[dst][0..63] ------------
__global__ void scatter_k(const ushort* __restrict__ X, const int* __restrict__ src,
                          const int* __restrict__ dst, float* __restrict__ agg, int koff) {
  int gid = blockIdx.x * blockDim.x + threadIdx.x;
  int e = gid >> 5, l = gid & 31;
  if (e >= NE) return;
  int s = src[e], d = dst[e];
  unsigned int two = *(const unsigned int*)(X + (size_t)s * D + koff + l * 2);
  atomicAdd(&agg[(size_t)d * 64 + l * 2],     bf2f((ushort)(two & 0xffffu)));
  atomicAdd(&agg[(size_t)d * 64 + l * 2 + 1], bf2f((ushort)(two >> 16)));
}

// ---- mean[:, koff..koff+63] = agg / max(cnt,1), cast bf16 ------------------
__global__ void mean_half_k(const float* __restrict__ agg, const int* __restrict__ cnt,
                            ushort* __restrict__ mean, int koff) {
  int i = blockIdx.x * blockDim.x + threadIdx.x;
  if (i >= NN * 16) return;
  int node = i >> 4, c4 = (i & 15) * 4;
  float c = (float)cnt[node]; if (c < 1.f) c = 1.f;
  float4 a = ((const float4*)agg)[i];
  ushort4 o;
  o.x = f2bf(a.x / c); o.y = f2bf(a.y / c);
  o.z = f2bf(a.z / c); o.w = f2bf(a.w / c);
  *(ushort4*)(mean + (size_t)node * D + koff + c4) = o;
}

// ---- Y = relu(A1@W1^T + A2@W2^T + bias), all [.,128] -----------------------
__global__ __launch_bounds__(256) void gemm_dual(
    const ushort* __restrict__ A1, const ushort* __restrict__ A2,
    const ushort* __restrict__ W1, const ushort* __restrict__ W2, int ldw,
    const ushort* __restrict__ bias, ushort* __restrict__ Y, int nrows)
{
  __shared__ ushort wlds[32 * 64 * 8];   // 32 KiB
  const int tid = threadIdx.x;
  const int wave = tid >> 6, lane = tid & 63;
  const int l15 = lane & 15, q = lane >> 4;
  const int m0 = blockIdx.x * 128 + wave * 32;

  f32x4 acc[2][8];
  #pragma unroll
  for (int rt = 0; rt < 2; ++rt)
    #pragma unroll
    for (int c = 0; c < 8; ++c) acc[rt][c] = (f32x4){0.f, 0.f, 0.f, 0.f};

  for (int phase = 0; phase < 2; ++phase) {
    const ushort* W = phase ? W2 : W1;
    const ushort* A = phase ? A2 : A1;
    __syncthreads();
    #pragma unroll
    for (int it = 0; it < 8; ++it) {
      int combo = it * 4 + wave;         // c = combo>>2, ks = combo&3
      int c = combo >> 2, ks = combo & 3;
      *(uint4*)(&wlds[(combo * 64 + lane) * 8]) =
          *(const uint4*)(W + (size_t)(c * 16 + l15) * ldw + ks * 32 + q * 8);
    }
    __syncthreads();
    #pragma unroll
    for (int ks = 0; ks < 4; ++ks) {
      short8 af[2];
      #pragma unroll
      for (int rt = 0; rt < 2; ++rt) {
        int row = m0 + rt * 16 + l15;
        if (row > nrows - 1) row = nrows - 1;   // clamp (stores are guarded)
        af[rt] = *(const short8*)(A + (size_t)row * D + ks * 32 + q * 8);
      }
      #pragma unroll
      for (int c = 0; c < 8; ++c) {
        short8 bf = *(const short8*)(&wlds[((c * 4 + ks) * 64 + lane) * 8]);
        acc[0][c] = __builtin_amdgcn_mfma_f32_16x16x32_bf16(af[0], bf, acc[0][c], 0, 0, 0);
        acc[1][c] = __builtin_amdgcn_mfma_f32_16x16x32_bf16(af[1], bf, acc[1][c], 0, 0, 0);
      }
    }
  }
  // C/D layout: col = lane&15, row = (lane>>4)*4 + r   [m89-verified]
  #pragma unroll
  for (int c = 0; c < 8; ++c) {
    float b = bf2f(bias[c * 16 + l15]);
    #pragma unroll
    for (int rt = 0; rt < 2; ++rt) {
      #pragma unroll
      for (int r = 0; r < 4; ++r) {
        int row = m0 + rt * 16 + q * 4 + r;
        if (row < nrows) {
          float v = acc[rt][c][r] + b;
          v = v > 0.f ? v : 0.f;
          Y[(size_t)row * D + c * 16 + l15] = f2bf(v);
        }
      }
    }
  }
}

// ---- out[e,:] = [x2[src]; x2[dst]] @ Wo^T + bo  (out dtype follows flags[0])
__global__ __launch_bounds__(256) void edge_k(
    const ushort* __restrict__ X, const int* __restrict__ src, const int* __restrict__ dst,
    const ushort* __restrict__ Wo, const ushort* __restrict__ bo,
    const int* __restrict__ flags, void* __restrict__ outv, int E)
{
  __shared__ ushort wlds[8 * 64 * 8];    // 8 KiB
  const int tid = threadIdx.x, wave = tid >> 6, lane = tid & 63;
  const int l15 = lane & 15, q = lane >> 4;
  #pragma unroll
  for (int it = 0; it < 2; ++it) {
    int ks = it * 4 + wave;              // 0..7 covers K=256
    *(uint4*)(&wlds[(ks * 64 + lane) * 8]) =
        *(const uint4*)(Wo + (size_t)l15 * 256 + ks * 32 + q * 8);
  }
  __syncthreads();
  const int f32out = flags[0];
  float bo_f = bf2f(bo[l15]);
  int ngroups = (E + 15) >> 4;
  int gstride = gridDim.x * 4;
  for (int g = blockIdx.x * 4 + wave; g < ngroups; g += gstride) {
    int e = g * 16 + l15; if (e > E - 1) e = E - 1;
    int s = src[e], d = dst[e];
    f32x4 acc = (f32x4){0.f, 0.f, 0.f, 0.f};
    #pragma unroll
    for (int ks = 0; ks < 8; ++ks) {
      const ushort* base = (ks < 4) ? (X + (size_t)s * D + ks * 32)
                                    : (X + (size_t)d * D + (ks - 4) * 32);
      short8 a  = *(const short8*)(base + q * 8);
      short8 bf = *(const short8*)(&wlds[(ks * 64 + lane) * 8]);
      acc = __builtin_amdgcn_mfma_f32_16x16x32_bf16(a, bf, acc, 0, 0, 0);
    }
    #pragma unroll
    for (int r = 0; r < 4; ++r) {
      int er = g * 16 + q * 4 + r;
      if (er < E) {
        float v = acc[r] + bo_f;
        if (f32out) ((float*)outv)[(size_t)er * NC + l15] = v;
        else        ((ushort*)outv)[(size_t)er * NC + l15] = f2bf(v);
      }
    }
  }
}

extern "C" void kernel_launch(void* const* d_in, const int* in_sizes, int n_in,
                              void* d_out, int out_size, void* d_ws, size_t ws_size,
                              hipStream_t stream) {
  const void* x_in = d_in[0];
  const int*  ei   = (const int*)d_in[1];

  // workspace layout (bytes): total 59.81 MB
  char* ws = (char*)d_ws;
  int*    idx   = (int*)(ws + 0);              //  8,000,000
  int*    cnt   = (int*)(ws + 8000000);        //    400,000
  int*    flags = (int*)(ws + 8400000);        //        256
  ushort* wb    = (ushort*)(ws + 8400256);     //    205,600
  float*  agg   = (float*)(ws + 8608000);      // 25,600,000 (buf1: agg / h)
  ushort* buf1  = (ushort*)(ws + 8608000);
  ushort* buf2  = (ushort*)(ws + 34208000);    // 25,600,000 (xb / meanL1 / x2)
  // d_out doubles as scratch for meanL0 then x1 (>=32MB, both <=25.6MB)
  ushort* dscr  = (ushort*)d_out;

  int* src = idx;
  int* dst = idx + NE;

  // canonical bf16 weight views
  ushort* Wl0 = wb + 0,      *Wr0 = wb + 16384, *Wl1 = wb + 32768, *Wr1 = wb + 49152;
  ushort* Wc  = wb + 65536,  *Wo  = wb + 98304;
  ushort* bl0 = wb + 102400, *bl1 = wb + 102528, *bc = wb + 102656, *bo = wb + 102784;

  WPtrs w;
  w.p[0] = d_in[2];  // W_l0
  w.p[1] = d_in[4];  // W_r0
  w.p[2] = d_in[5];  // W_l1
  w.p[3] = d_in[7];  // W_r1
  w.p[4] = d_in[8];  // W_c
  w.p[5] = d_in[10]; // W_o
  w.p[6] = d_in[3];  // b_l0
  w.p[7] = d_in[6];  // b_l1
  w.p[8] = d_in[9];  // b_c
  w.p[9] = d_in[11]; // b_o

  const int gblocks = (NN + 127) / 128;        // 782
  const int n4 = NN * D / 4;

  sniff_k<<<1, 64, 0, stream>>>((const ushort*)x_in, (const unsigned int*)ei, flags);
  convert_idx_k<<<(2 * NE + 255) / 256, 256, 0, stream>>>(ei, flags, idx, 2 * NE);
  convert_x_k<<<(n4 + 255) / 256, 256, 0, stream>>>(x_in, flags, buf2);
  convert_w_k<<<(WTOT + 255) / 256, 256, 0, stream>>>(w, flags, wb);

  (void)hipMemsetAsync(cnt, 0, NN * sizeof(int), stream);
  count_k<<<(NE + 255) / 256, 256, 0, stream>>>(dst, cnt, NE);

  const int sgrid = (NE * 32) / 256;           // 125,000 blocks
  const int mgrid = (NN * 16 + 255) / 256;

  // ---- layer 0: x=buf2, mean->d_out, h->buf1, x1->d_out --------------------
  (void)hipMemsetAsync(agg, 0, (size_t)NN * 64 * 4, stream);
  scatter_k<<<sgrid, 256, 0, stream>>>(buf2, src, dst, agg, 0);
  mean_half_k<<<mgrid, 256, 0, stream>>>(agg, cnt, dscr, 0);
  (void)hipMemsetAsync(agg, 0, (size_t)NN * 64 * 4, stream);
  scatter_k<<<sgrid, 256, 0, stream>>>(buf2, src, dst, agg, 64);
  mean_half_k<<<mgrid, 256, 0, stream>>>(agg, cnt, dscr, 64);
  gemm_dual<<<gblocks, 256, 0, stream>>>(dscr, buf2, Wl0, Wr0, D, bl0, buf1, NN);      // h
  gemm_dual<<<gblocks, 256, 0, stream>>>(buf2, buf1, Wc, Wc + D, 2 * D, bc, dscr, NN); // x1

  // ---- layer 1: x1=d_out, mean->buf2, h->buf1, x2->buf2 --------------------
  (void)hipMemsetAsync(agg, 0, (size_t)NN * 64 * 4, stream);
  scatter_k<<<sgrid, 256, 0, stream>>>(dscr, src, dst, agg, 0);
  mean_half_k<<<mgrid, 256, 0, stream>>>(agg, cnt, buf2, 0);
  (void)hipMemsetAsync(agg, 0, (size_t)NN * 64 * 4, stream);
  scatter_k<<<sgrid, 256, 0, stream>>>(dscr, src, dst, agg, 64);
  mean_half_k<<<mgrid, 256, 0, stream>>>(agg, cnt, buf2, 64);
  gemm_dual<<<gblocks, 256, 0, stream>>>(buf2, dscr, Wl1, Wr1, D, bl1, buf1, NN);      // h
  gemm_dual<<<gblocks, 256, 0, stream>>>(dscr, buf1, Wc, Wc + D, 2 * D, bc, buf2, NN); // x2

  // ---- edge classifier -----------------------------------------------------
  edge_k<<<1024, 256, 0, stream>>>(buf2, src, dst, Wo, bo, flags, d_out, NE);
}

// Round 5
// 821.467 us; speedup vs baseline: 2.4872x; 2.4872x over previous
//
#include <hip/hip_runtime.h>
#include <hip/hip_bf16.h>

#define NN 100000      // nodes
#define NE 1000000     // edges
#define D  128         // hidden / input dim
#define NC 16          // classes

typedef short short8 __attribute__((ext_vector_type(8)));
typedef float f32x4  __attribute__((ext_vector_type(4)));

__device__ __forceinline__ float bf2f(ushort u) {
  union { unsigned int i; float f; } v; v.i = ((unsigned int)u) << 16; return v.f;
}
__device__ __forceinline__ ushort f2bf(float f) {
  union { float f; unsigned int i; } v; v.f = f;
  unsigned int x = v.i;
  return (ushort)((x + 0x7FFFu + ((x >> 16) & 1u)) >> 16);  // RNE
}

// ---- sniff dtypes: flags[0]=1 if float tensors are f32; flags[1]=1 if idx int64
__global__ void sniff_k(const ushort* __restrict__ xr, const unsigned int* __restrict__ ei,
                        int* __restrict__ flags) {
  if (threadIdx.x != 0 || blockIdx.x != 0) return;
  int f32 = 0;
  for (int i = 0; i < 128; ++i) {
    unsigned int e = ((unsigned int)xr[i] >> 7) & 0xFFu;
    if (e < 97u || e > 157u) f32 = 1;
  }
  flags[0] = f32;
  unsigned int s = 0;
  for (int i = 1; i < 256; i += 2) s |= ei[i];   // int64 < 2^31 => hi words all 0
  flags[1] = (s == 0) ? 1 : 0;
}

// ---- materialize clean int32 indices, clamped to [0,NN) ---------------------
__global__ void convert_idx_k(const int* __restrict__ ei, const int* __restrict__ flags,
                              int* __restrict__ idx, int n) {
  int i = blockIdx.x * blockDim.x + threadIdx.x;
  if (i >= n) return;
  int v = flags[1] ? ei[2 * i] : ei[i];   // int64: take low word
  v = v < 0 ? 0 : (v >= NN ? NN - 1 : v);
  idx[i] = v;
}

// ---- convert x to canonical bf16 -------------------------------------------
__global__ void convert_x_k(const void* __restrict__ xin, const int* __restrict__ flags,
                            ushort* __restrict__ xb) {
  int i = blockIdx.x * blockDim.x + threadIdx.x;
  const int n4 = NN * D / 4;
  if (i >= n4) return;
  ushort4 o;
  if (flags[0]) {
    float4 v = ((const float4*)xin)[i];
    o.x = f2bf(v.x); o.y = f2bf(v.y); o.z = f2bf(v.z); o.w = f2bf(v.w);
  } else {
    o = ((const ushort4*)xin)[i];
  }
  ((ushort4*)xb)[i] = o;
}

// ---- convert all weights/biases to canonical bf16 block --------------------
struct WPtrs { const void* p[10]; };
#define WTOT 102800
__global__ void convert_w_k(WPtrs w, const int* __restrict__ flags, ushort* __restrict__ wb) {
  const int off[10] = {0, 16384, 32768, 49152, 65536, 98304, 102400, 102528, 102656, 102784};
  int i = blockIdx.x * blockDim.x + threadIdx.x;
  if (i >= WTOT) return;
  int seg = 0;
  #pragma unroll
  for (int s2 = 1; s2 < 10; ++s2) if (i >= off[s2]) seg = s2;
  int j = i - off[seg];
  wb[i] = flags[0] ? f2bf(((const float*)w.p[seg])[j]) : ((const ushort*)w.p[seg])[j];
}

// ---- degree count -----------------------------------------------------------
__global__ void count_k(const int* __restrict__ dst, int* __restrict__ cnt, int E) {
  int e = blockIdx.x * blockDim.x + threadIdx.x;
  if (e < E) atomicAdd(&cnt[dst[e]], 1);
}

// ---- exclusive prefix sum over cnt -> off[NN+1], cur[NN] (single block) -----
#define SCAN_PER 391   // 391*256 >= NN
__global__ void scan_k(const int* __restrict__ cnt, int* __restrict__ off,
                       int* __restrict__ cur) {
  __shared__ int lsum[256];
  const int t = threadIdx.x;
  const int n0 = t * SCAN_PER;
  const int n1 = (n0 + SCAN_PER < NN) ? n0 + SCAN_PER : NN;
  int s = 0;
  for (int n = n0; n < n1; ++n) s += cnt[n];
  lsum[t] = s;
  __syncthreads();
  if (t == 0) {
    int run = 0;
    for (int i = 0; i < 256; ++i) { int v = lsum[i]; lsum[i] = run; run += v; }
  }
  __syncthreads();
  int run = lsum[t];
  for (int n = n0; n < n1; ++n) { off[n] = run; cur[n] = run; run += cnt[n]; }
  if (t == 255) off[NN] = run;   // == NE
}

// ---- bucket: nbr[] = src ids grouped by dst (CSR) ---------------------------
__global__ void bucket_k(const int* __restrict__ src, const int* __restrict__ dst,
                         int* __restrict__ cur, int* __restrict__ nbr, int E) {
  int e = blockIdx.x * blockDim.x + threadIdx.x;
  if (e >= E) return;
  int pos = atomicAdd(&cur[dst[e]], 1);
  nbr[pos] = src[e];
}

// ---- segmented mean: one wave per node, 64 lanes x 2 f32 acc = 128 dims -----
__global__ __launch_bounds__(256) void agg_k(
    const ushort* __restrict__ X, const int* __restrict__ nbr,
    const int* __restrict__ off, ushort* __restrict__ mean) {
  const int wave = threadIdx.x >> 6, lane = threadIdx.x & 63;
  const int node = blockIdx.x * 4 + wave;
  if (node >= NN) return;
  const int j0 = off[node], j1 = off[node + 1];
  float a0 = 0.f, a1 = 0.f;
  int j = j0;
  for (; j + 1 < j1; j += 2) {    // 2 edges/iter for load ILP
    int s0 = nbr[j], s1 = nbr[j + 1];
    unsigned int v0 = *(const unsigned int*)(X + (size_t)s0 * D + lane * 2);
    unsigned int v1 = *(const unsigned int*)(X + (size_t)s1 * D + lane * 2);
    a0 += bf2f((ushort)(v0 & 0xffffu)) + bf2f((ushort)(v1 & 0xffffu));
    a1 += bf2f((ushort)(v0 >> 16))     + bf2f((ushort)(v1 >> 16));
  }
  if (j < j1) {
    unsigned int v0 = *(const unsigned int*)(X + (size_t)nbr[j] * D + lane * 2);
    a0 += bf2f((ushort)(v0 & 0xffffu));
    a1 += bf2f((ushort)(v0 >> 16));
  }
  int deg = j1 - j0;
  float inv = 1.f / (float)(deg > 1 ? deg : 1);
  unsigned int o = (unsigned int)f2bf(a0 * inv) | ((unsigned int)f2bf(a1 * inv) << 16);
  *(unsigned int*)(mean + (size_t)node * D + lane * 2) = o;
}

// ---- Y = relu(A1@W1^T + A2@W2^T + bias), all [.,128] -----------------------
__global__ __launch_bounds__(256) void gemm_dual(
    const ushort* __restrict__ A1, const ushort* __restrict__ A2,
    const ushort* __restrict__ W1, const ushort* __restrict__ W2, int ldw,
    const ushort* __restrict__ bias, ushort* __restrict__ Y, int nrows)
{
  __shared__ ushort wlds[32 * 64 * 8];   // 32 KiB
  const int tid = threadIdx.x;
  const int wave = tid >> 6, lane = tid & 63;
  const int l15 = lane & 15, q = lane >> 4;
  const int m0 = blockIdx.x * 128 + wave * 32;

  f32x4 acc[2][8];
  #pragma unroll
  for (int rt = 0; rt < 2; ++rt)
    #pragma unroll
    for (int c = 0; c < 8; ++c) acc[rt][c] = (f32x4){0.f, 0.f, 0.f, 0.f};

  for (int phase = 0; phase < 2; ++phase) {
    const ushort* W = phase ? W2 : W1;
    const ushort* A = phase ? A2 : A1;
    __syncthreads();
    #pragma unroll
    for (int it = 0; it < 8; ++it) {
      int combo = it * 4 + wave;         // c = combo>>2, ks = combo&3
      int c = combo >> 2, ks = combo & 3;
      *(uint4*)(&wlds[(combo * 64 + lane) * 8]) =
          *(const uint4*)(W + (size_t)(c * 16 + l15) * ldw + ks * 32 + q * 8);
    }
    __syncthreads();
    #pragma unroll
    for (int ks = 0; ks < 4; ++ks) {
      short8 af[2];
      #pragma unroll
      for (int rt = 0; rt < 2; ++rt) {
        int row = m0 + rt * 16 + l15;
        if (row > nrows - 1) row = nrows - 1;   // clamp (stores are guarded)
        af[rt] = *(const short8*)(A + (size_t)row * D + ks * 32 + q * 8);
      }
      #pragma unroll
      for (int c = 0; c < 8; ++c) {
        short8 bf = *(const short8*)(&wlds[((c * 4 + ks) * 64 + lane) * 8]);
        acc[0][c] = __builtin_amdgcn_mfma_f32_16x16x32_bf16(af[0], bf, acc[0][c], 0, 0, 0);
        acc[1][c] = __builtin_amdgcn_mfma_f32_16x16x32_bf16(af[1], bf, acc[1][c], 0, 0, 0);
      }
    }
  }
  // C/D layout: col = lane&15, row = (lane>>4)*4 + r   [m89-verified]
  #pragma unroll
  for (int c = 0; c < 8; ++c) {
    float b = bf2f(bias[c * 16 + l15]);
    #pragma unroll
    for (int rt = 0; rt < 2; ++rt) {
      #pragma unroll
      for (int r = 0; r < 4; ++r) {
        int row = m0 + rt * 16 + q * 4 + r;
        if (row < nrows) {
          float v = acc[rt][c][r] + b;
          v = v > 0.f ? v : 0.f;
          Y[(size_t)row * D + c * 16 + l15] = f2bf(v);
        }
      }
    }
  }
}

// ---- out[e,:] = [x2[src]; x2[dst]] @ Wo^T + bo  (out dtype follows flags[0])
__global__ __launch_bounds__(256) void edge_k(
    const ushort* __restrict__ X, const int* __restrict__ src, const int* __restrict__ dst,
    const ushort* __restrict__ Wo, const ushort* __restrict__ bo,
    const int* __restrict__ flags, void* __restrict__ outv, int E)
{
  __shared__ ushort wlds[8 * 64 * 8];    // 8 KiB
  const int tid = threadIdx.x, wave = tid >> 6, lane = tid & 63;
  const int l15 = lane & 15, q = lane >> 4;
  #pragma unroll
  for (int it = 0; it < 2; ++it) {
    int ks = it * 4 + wave;              // 0..7 covers K=256
    *(uint4*)(&wlds[(ks * 64 + lane) * 8]) =
        *(const uint4*)(Wo + (size_t)l15 * 256 + ks * 32 + q * 8);
  }
  __syncthreads();
  const int f32out = flags[0];
  float bo_f = bf2f(bo[l15]);
  int ngroups = (E + 15) >> 4;
  int gstride = gridDim.x * 4;
  for (int g = blockIdx.x * 4 + wave; g < ngroups; g += gstride) {
    int e = g * 16 + l15; if (e > E - 1) e = E - 1;
    int s = src[e], d = dst[e];
    f32x4 acc = (f32x4){0.f, 0.f, 0.f, 0.f};
    #pragma unroll
    for (int ks = 0; ks < 8; ++ks) {
      const ushort* base = (ks < 4) ? (X + (size_t)s * D + ks * 32)
                                    : (X + (size_t)d * D + (ks - 4) * 32);
      short8 a  = *(const short8*)(base + q * 8);
      short8 bf = *(const short8*)(&wlds[(ks * 64 + lane) * 8]);
      acc = __builtin_amdgcn_mfma_f32_16x16x32_bf16(a, bf, acc, 0, 0, 0);
    }
    #pragma unroll
    for (int r = 0; r < 4; ++r) {
      int er = g * 16 + q * 4 + r;
      if (er < E) {
        float v = acc[r] + bo_f;
        if (f32out) ((float*)outv)[(size_t)er * NC + l15] = v;
        else        ((ushort*)outv)[(size_t)er * NC + l15] = f2bf(v);
      }
    }
  }
}

extern "C" void kernel_launch(void* const* d_in, const int* in_sizes, int n_in,
                              void* d_out, int out_size, void* d_ws, size_t ws_size,
                              hipStream_t stream) {
  const void* x_in = d_in[0];
  const int*  ei   = (const int*)d_in[1];

  // workspace layout (bytes): total ~64.6 MB (round-1 evidence: ws >= ~111 MB)
  char* ws = (char*)d_ws;
  int*    idx   = (int*)(ws + 0);              //  8,000,000 (src | dst)
  int*    cnt   = (int*)(ws + 8000000);        //    400,000
  int*    flags = (int*)(ws + 8400000);        //        256
  ushort* wb    = (ushort*)(ws + 8400256);     //    205,600
  int*    off   = (int*)(ws + 8605856);        //    400,004
  int*    cur   = (int*)(ws + 9005872);        //    400,000
  int*    nbr   = (int*)(ws + 9405872);        //  4,000,000
  ushort* buf1  = (ushort*)(ws + 13405888);    // 25,600,000 (h)
  ushort* buf2  = (ushort*)(ws + 39005888);    // 25,600,000 (xb / meanL1 / x2)
  ushort* dscr  = (ushort*)d_out;              // d_out scratch: meanL0 / x1

  int* src = idx;
  int* dst = idx + NE;

  ushort* Wl0 = wb + 0,      *Wr0 = wb + 16384, *Wl1 = wb + 32768, *Wr1 = wb + 49152;
  ushort* Wc  = wb + 65536,  *Wo  = wb + 98304;
  ushort* bl0 = wb + 102400, *bl1 = wb + 102528, *bc = wb + 102656, *bo = wb + 102784;

  WPtrs w;
  w.p[0] = d_in[2];  w.p[1] = d_in[4];  w.p[2] = d_in[5];  w.p[3] = d_in[7];
  w.p[4] = d_in[8];  w.p[5] = d_in[10]; w.p[6] = d_in[3];  w.p[7] = d_in[6];
  w.p[8] = d_in[9];  w.p[9] = d_in[11];

  const int gblocks = (NN + 127) / 128;        // 782
  const int n4 = NN * D / 4;
  const int agrid = (NN + 3) / 4;              // 25,000 (4 nodes/block)

  sniff_k<<<1, 64, 0, stream>>>((const ushort*)x_in, (const unsigned int*)ei, flags);
  convert_idx_k<<<(2 * NE + 255) / 256, 256, 0, stream>>>(ei, flags, idx, 2 * NE);
  convert_x_k<<<(n4 + 255) / 256, 256, 0, stream>>>(x_in, flags, buf2);
  convert_w_k<<<(WTOT + 255) / 256, 256, 0, stream>>>(w, flags, wb);

  // ---- build CSR (dst-grouped src list) — once, reused by both layers ------
  (void)hipMemsetAsync(cnt, 0, NN * sizeof(int), stream);
  count_k<<<(NE + 255) / 256, 256, 0, stream>>>(dst, cnt, NE);
  scan_k<<<1, 256, 0, stream>>>(cnt, off, cur);
  bucket_k<<<(NE + 255) / 256, 256, 0, stream>>>(src, dst, cur, nbr, NE);

  // ---- layer 0: x=buf2 -> mean=dscr -> h=buf1 -> x1=dscr -------------------
  agg_k<<<agrid, 256, 0, stream>>>(buf2, nbr, off, dscr);
  gemm_dual<<<gblocks, 256, 0, stream>>>(dscr, buf2, Wl0, Wr0, D, bl0, buf1, NN);      // h
  gemm_dual<<<gblocks, 256, 0, stream>>>(buf2, buf1, Wc, Wc + D, 2 * D, bc, dscr, NN); // x1

  // ---- layer 1: x1=dscr -> mean=buf2 -> h=buf1 -> x2=buf2 ------------------
  agg_k<<<agrid, 256, 0, stream>>>(dscr, nbr, off, buf2);
  gemm_dual<<<gblocks, 256, 0, stream>>>(buf2, dscr, Wl1, Wr1, D, bl1, buf1, NN);      // h
  gemm_dual<<<gblocks, 256, 0, stream>>>(dscr, buf1, Wc, Wc + D, 2 * D, bc, buf2, NN); // x2

  // ---- edge classifier -----------------------------------------------------
  edge_k<<<1024, 256, 0, stream>>>(buf2, src, dst, Wo, bo, flags, d_out, NE);
}

// Round 6
// 599.108 us; speedup vs baseline: 3.4103x; 1.3712x over previous
//
#include <hip/hip_runtime.h>
#include <hip/hip_bf16.h>

#define NN 100000      // nodes
#define NE 1000000     // edges
#define D  128         // hidden / input dim
#define NC 16          // classes

typedef short short8 __attribute__((ext_vector_type(8)));
typedef float f32x4  __attribute__((ext_vector_type(4)));

__device__ __forceinline__ float bf2f(ushort u) {
  union { unsigned int i; float f; } v; v.i = ((unsigned int)u) << 16; return v.f;
}
__device__ __forceinline__ ushort f2bf(float f) {
  union { float f; unsigned int i; } v; v.f = f;
  unsigned int x = v.i;
  return (ushort)((x + 0x7FFFu + ((x >> 16) & 1u)) >> 16);  // RNE
}

// ---- sniff dtypes: flags[0]=1 if float tensors are f32; flags[1]=1 if idx int64
__global__ void sniff_k(const ushort* __restrict__ xr, const unsigned int* __restrict__ ei,
                        int* __restrict__ flags) {
  if (threadIdx.x != 0 || blockIdx.x != 0) return;
  int f32 = 0;
  for (int i = 0; i < 128; ++i) {
    unsigned int e = ((unsigned int)xr[i] >> 7) & 0xFFu;
    if (e < 97u || e > 157u) f32 = 1;
  }
  flags[0] = f32;
  unsigned int s = 0;
  for (int i = 1; i < 256; i += 2) s |= ei[i];   // int64 < 2^31 => hi words all 0
  flags[1] = (s == 0) ? 1 : 0;
}

// ---- materialize clean int32 indices, clamped to [0,NN) ---------------------
__global__ void convert_idx_k(const int* __restrict__ ei, const int* __restrict__ flags,
                              int* __restrict__ idx, int n) {
  int i = blockIdx.x * blockDim.x + threadIdx.x;
  if (i >= n) return;
  int v = flags[1] ? ei[2 * i] : ei[i];   // int64: take low word
  v = v < 0 ? 0 : (v >= NN ? NN - 1 : v);
  idx[i] = v;
}

// ---- convert x to canonical bf16 -------------------------------------------
__global__ void convert_x_k(const void* __restrict__ xin, const int* __restrict__ flags,
                            ushort* __restrict__ xb) {
  int i = blockIdx.x * blockDim.x + threadIdx.x;
  const int n4 = NN * D / 4;
  if (i >= n4) return;
  ushort4 o;
  if (flags[0]) {
    float4 v = ((const float4*)xin)[i];
    o.x = f2bf(v.x); o.y = f2bf(v.y); o.z = f2bf(v.z); o.w = f2bf(v.w);
  } else {
    o = ((const ushort4*)xin)[i];
  }
  ((ushort4*)xb)[i] = o;
}

// ---- convert all weights/biases to canonical bf16 block --------------------
struct WPtrs { const void* p[10]; };
#define WTOT 102800
__global__ void convert_w_k(WPtrs w, const int* __restrict__ flags, ushort* __restrict__ wb) {
  const int off[10] = {0, 16384, 32768, 49152, 65536, 98304, 102400, 102528, 102656, 102784};
  int i = blockIdx.x * blockDim.x + threadIdx.x;
  if (i >= WTOT) return;
  int seg = 0;
  #pragma unroll
  for (int s2 = 1; s2 < 10; ++s2) if (i >= off[s2]) seg = s2;
  int j = i - off[seg];
  wb[i] = flags[0] ? f2bf(((const float*)w.p[seg])[j]) : ((const ushort*)w.p[seg])[j];
}

// ---- degree count -----------------------------------------------------------
__global__ void count_k(const int* __restrict__ dst, int* __restrict__ cnt, int E) {
  int e = blockIdx.x * blockDim.x + threadIdx.x;
  if (e < E) atomicAdd(&cnt[dst[e]], 1);
}

// ---- hierarchical exclusive scan: cnt[NN] -> off[NN+1], cur[NN] -------------
#define NCHUNK ((NN + 255) / 256)   // 391
__global__ void scan1_k(const int* __restrict__ cnt, int* __restrict__ csum) {
  __shared__ int tmp[256];
  int i = blockIdx.x * 256 + threadIdx.x;
  tmp[threadIdx.x] = (i < NN) ? cnt[i] : 0;
  __syncthreads();
  #pragma unroll
  for (int s = 128; s > 0; s >>= 1) {
    if (threadIdx.x < s) tmp[threadIdx.x] += tmp[threadIdx.x + s];
    __syncthreads();
  }
  if (threadIdx.x == 0) csum[blockIdx.x] = tmp[0];
}
__global__ void scan2_k(int* __restrict__ csum) {   // 1 block, 512 thr, n=NCHUNK
  __shared__ int tmp[512];
  int t = threadIdx.x;
  int self = (t < NCHUNK) ? csum[t] : 0;
  tmp[t] = self;
  __syncthreads();
  for (int s = 1; s < 512; s <<= 1) {
    int v = (t >= s) ? tmp[t - s] : 0;
    __syncthreads();
    tmp[t] += v;
    __syncthreads();
  }
  if (t < NCHUNK) csum[t] = tmp[t] - self;   // exclusive
}
__global__ void scan3_k(const int* __restrict__ cnt, const int* __restrict__ csum,
                        int* __restrict__ off, int* __restrict__ cur) {
  __shared__ int tmp[256];
  int i = blockIdx.x * 256 + threadIdx.x;
  int t = threadIdx.x;
  int self = (i < NN) ? cnt[i] : 0;
  tmp[t] = self;
  __syncthreads();
  for (int s = 1; s < 256; s <<= 1) {
    int v = (t >= s) ? tmp[t - s] : 0;
    __syncthreads();
    tmp[t] += v;
    __syncthreads();
  }
  int excl = csum[blockIdx.x] + tmp[t] - self;
  if (i < NN) { off[i] = excl; cur[i] = excl; }
  if (i == NN - 1) off[NN] = excl + self;
}

// ---- bucket: nbr[] = src ids grouped by dst (CSR) ---------------------------
__global__ void bucket_k(const int* __restrict__ src, const int* __restrict__ dst,
                         int* __restrict__ cur, int* __restrict__ nbr, int E) {
  int e = blockIdx.x * blockDim.x + threadIdx.x;
  if (e >= E) return;
  int pos = atomicAdd(&cur[dst[e]], 1);
  nbr[pos] = src[e];
}

// ---- segmented mean: one wave per node, 64 lanes x 2 f32 acc = 128 dims -----
__global__ __launch_bounds__(256) void agg_k(
    const ushort* __restrict__ X, const int* __restrict__ nbr,
    const int* __restrict__ off, ushort* __restrict__ mean) {
  const int wave = threadIdx.x >> 6, lane = threadIdx.x & 63;
  const int node = blockIdx.x * 4 + wave;
  if (node >= NN) return;
  const int j0 = off[node], j1 = off[node + 1];
  float a0 = 0.f, a1 = 0.f;
  int j = j0;
  for (; j + 1 < j1; j += 2) {    // 2 edges/iter for load ILP
    int s0 = nbr[j], s1 = nbr[j + 1];
    unsigned int v0 = *(const unsigned int*)(X + (size_t)s0 * D + lane * 2);
    unsigned int v1 = *(const unsigned int*)(X + (size_t)s1 * D + lane * 2);
    a0 += bf2f((ushort)(v0 & 0xffffu)) + bf2f((ushort)(v1 & 0xffffu));
    a1 += bf2f((ushort)(v0 >> 16))     + bf2f((ushort)(v1 >> 16));
  }
  if (j < j1) {
    unsigned int v0 = *(const unsigned int*)(X + (size_t)nbr[j] * D + lane * 2);
    a0 += bf2f((ushort)(v0 & 0xffffu));
    a1 += bf2f((ushort)(v0 >> 16));
  }
  int deg = j1 - j0;
  float inv = 1.f / (float)(deg > 1 ? deg : 1);
  unsigned int o = (unsigned int)f2bf(a0 * inv) | ((unsigned int)f2bf(a1 * inv) << 16);
  *(unsigned int*)(mean + (size_t)node * D + lane * 2) = o;
}

// ---- Y = relu(A1@W1^T + A2@W2^T + bias), all [.,128] -----------------------
__global__ __launch_bounds__(256) void gemm_dual(
    const ushort* __restrict__ A1, const ushort* __restrict__ A2,
    const ushort* __restrict__ W1, const ushort* __restrict__ W2, int ldw,
    const ushort* __restrict__ bias, ushort* __restrict__ Y, int nrows)
{
  __shared__ ushort wlds[32 * 64 * 8];   // 32 KiB
  const int tid = threadIdx.x;
  const int wave = tid >> 6, lane = tid & 63;
  const int l15 = lane & 15, q = lane >> 4;
  const int m0 = blockIdx.x * 128 + wave * 32;

  f32x4 acc[2][8];
  #pragma unroll
  for (int rt = 0; rt < 2; ++rt)
    #pragma unroll
    for (int c = 0; c < 8; ++c) acc[rt][c] = (f32x4){0.f, 0.f, 0.f, 0.f};

  for (int phase = 0; phase < 2; ++phase) {
    const ushort* W = phase ? W2 : W1;
    const ushort* A = phase ? A2 : A1;
    __syncthreads();
    #pragma unroll
    for (int it = 0; it < 8; ++it) {
      int combo = it * 4 + wave;         // c = combo>>2, ks = combo&3
      int c = combo >> 2, ks = combo & 3;
      *(uint4*)(&wlds[(combo * 64 + lane) * 8]) =
          *(const uint4*)(W + (size_t)(c * 16 + l15) * ldw + ks * 32 + q * 8);
    }
    __syncthreads();
    #pragma unroll
    for (int ks = 0; ks < 4; ++ks) {
      short8 af[2];
      #pragma unroll
      for (int rt = 0; rt < 2; ++rt) {
        int row = m0 + rt * 16 + l15;
        if (row > nrows - 1) row = nrows - 1;   // clamp (stores are guarded)
        af[rt] = *(const short8*)(A + (size_t)row * D + ks * 32 + q * 8);
      }
      #pragma unroll
      for (int c = 0; c < 8; ++c) {
        short8 bf = *(const short8*)(&wlds[((c * 4 + ks) * 64 + lane) * 8]);
        acc[0][c] = __builtin_amdgcn_mfma_f32_16x16x32_bf16(af[0], bf, acc[0][c], 0, 0, 0);
        acc[1][c] = __builtin_amdgcn_mfma_f32_16x16x32_bf16(af[1], bf, acc[1][c], 0, 0, 0);
      }
    }
  }
  // C/D layout: col = lane&15, row = (lane>>4)*4 + r   [m89-verified]
  #pragma unroll
  for (int c = 0; c < 8; ++c) {
    float b = bf2f(bias[c * 16 + l15]);
    #pragma unroll
    for (int rt = 0; rt < 2; ++rt) {
      #pragma unroll
      for (int r = 0; r < 4; ++r) {
        int row = m0 + rt * 16 + q * 4 + r;
        if (row < nrows) {
          float v = acc[rt][c][r] + b;
          v = v > 0.f ? v : 0.f;
          Y[(size_t)row * D + c * 16 + l15] = f2bf(v);
        }
      }
    }
  }
}

// ---- out[e,:] = [x2[src]; x2[dst]] @ Wo^T + bo  (out dtype follows flags[0])
__global__ __launch_bounds__(256) void edge_k(
    const ushort* __restrict__ X, const int* __restrict__ src, const int* __restrict__ dst,
    const ushort* __restrict__ Wo, const ushort* __restrict__ bo,
    const int* __restrict__ flags, void* __restrict__ outv, int E)
{
  __shared__ ushort wlds[8 * 64 * 8];    // 8 KiB
  const int tid = threadIdx.x, wave = tid >> 6, lane = tid & 63;
  const int l15 = lane & 15, q = lane >> 4;
  #pragma unroll
  for (int it = 0; it < 2; ++it) {
    int ks = it * 4 + wave;              // 0..7 covers K=256
    *(uint4*)(&wlds[(ks * 64 + lane) * 8]) =
        *(const uint4*)(Wo + (size_t)l15 * 256 + ks * 32 + q * 8);
  }
  __syncthreads();
  const int f32out = flags[0];
  float bo_f = bf2f(bo[l15]);
  int ngroups = (E + 15) >> 4;
  int gstride = gridDim.x * 4;
  for (int g = blockIdx.x * 4 + wave; g < ngroups; g += gstride) {
    int e = g * 16 + l15; if (e > E - 1) e = E - 1;
    int s = src[e], d = dst[e];
    f32x4 acc = (f32x4){0.f, 0.f, 0.f, 0.f};
    #pragma unroll
    for (int ks = 0; ks < 8; ++ks) {
      const ushort* base = (ks < 4) ? (X + (size_t)s * D + ks * 32)
                                    : (X + (size_t)d * D + (ks - 4) * 32);
      short8 a  = *(const short8*)(base + q * 8);
      short8 bf = *(const short8*)(&wlds[(ks * 64 + lane) * 8]);
      acc = __builtin_amdgcn_mfma_f32_16x16x32_bf16(a, bf, acc, 0, 0, 0);
    }
    #pragma unroll
    for (int r = 0; r < 4; ++r) {
      int er = g * 16 + q * 4 + r;
      if (er < E) {
        float v = acc[r] + bo_f;
        if (f32out) ((float*)outv)[(size_t)er * NC + l15] = v;
        else        ((ushort*)outv)[(size_t)er * NC + l15] = f2bf(v);
      }
    }
  }
}

extern "C" void kernel_launch(void* const* d_in, const int* in_sizes, int n_in,
                              void* d_out, int out_size, void* d_ws, size_t ws_size,
                              hipStream_t stream) {
  const void* x_in = d_in[0];
  const int*  ei   = (const int*)d_in[1];

  // workspace layout (bytes): total ~64.6 MB
  char* ws = (char*)d_ws;
  int*    idx   = (int*)(ws + 0);              //  8,000,000 (src | dst)
  int*    cnt   = (int*)(ws + 8000000);        //    400,000
  int*    flags = (int*)(ws + 8400000);        //        256
  ushort* wb    = (ushort*)(ws + 8400256);     //    205,600
  int*    off   = (int*)(ws + 8605856);        //    400,004
  int*    cur   = (int*)(ws + 9005872);        //    400,000
  int*    nbr   = (int*)(ws + 9405872);        //  4,000,000
  int*    csum  = (int*)(ws + 13405872);       //      1,564 (NCHUNK ints)
  ushort* buf1  = (ushort*)(ws + 13407440);    // 25,600,000 (h)
  ushort* buf2  = (ushort*)(ws + 39007440);    // 25,600,000 (xb / meanL1 / x2)
  ushort* dscr  = (ushort*)d_out;              // d_out scratch: meanL0 / x1

  int* src = idx;
  int* dst = idx + NE;

  ushort* Wl0 = wb + 0,      *Wr0 = wb + 16384, *Wl1 = wb + 32768, *Wr1 = wb + 49152;
  ushort* Wc  = wb + 65536,  *Wo  = wb + 98304;
  ushort* bl0 = wb + 102400, *bl1 = wb + 102528, *bc = wb + 102656, *bo = wb + 102784;

  WPtrs w;
  w.p[0] = d_in[2];  w.p[1] = d_in[4];  w.p[2] = d_in[5];  w.p[3] = d_in[7];
  w.p[4] = d_in[8];  w.p[5] = d_in[10]; w.p[6] = d_in[3];  w.p[7] = d_in[6];
  w.p[8] = d_in[9];  w.p[9] = d_in[11];

  const int gblocks = (NN + 127) / 128;        // 782
  const int n4 = NN * D / 4;
  const int agrid = (NN + 3) / 4;              // 25,000 (4 nodes/block)

  sniff_k<<<1, 64, 0, stream>>>((const ushort*)x_in, (const unsigned int*)ei, flags);
  convert_idx_k<<<(2 * NE + 255) / 256, 256, 0, stream>>>(ei, flags, idx, 2 * NE);
  convert_x_k<<<(n4 + 255) / 256, 256, 0, stream>>>(x_in, flags, buf2);
  convert_w_k<<<(WTOT + 255) / 256, 256, 0, stream>>>(w, flags, wb);

  // ---- build CSR (dst-grouped src list) — once, reused by both layers ------
  (void)hipMemsetAsync(cnt, 0, NN * sizeof(int), stream);
  count_k<<<(NE + 255) / 256, 256, 0, stream>>>(dst, cnt, NE);
  scan1_k<<<NCHUNK, 256, 0, stream>>>(cnt, csum);
  scan2_k<<<1, 512, 0, stream>>>(csum);
  scan3_k<<<NCHUNK, 256, 0, stream>>>(cnt, csum, off, cur);
  bucket_k<<<(NE + 255) / 256, 256, 0, stream>>>(src, dst, cur, nbr, NE);

  // ---- layer 0: x=buf2 -> mean=dscr -> h=buf1 -> x1=dscr -------------------
  agg_k<<<agrid, 256, 0, stream>>>(buf2, nbr, off, dscr);
  gemm_dual<<<gblocks, 256, 0, stream>>>(dscr, buf2, Wl0, Wr0, D, bl0, buf1, NN);      // h
  gemm_dual<<<gblocks, 256, 0, stream>>>(buf2, buf1, Wc, Wc + D, 2 * D, bc, dscr, NN); // x1

  // ---- layer 1: x1=dscr -> mean=buf2 -> h=buf1 -> x2=buf2 ------------------
  agg_k<<<agrid, 256, 0, stream>>>(dscr, nbr, off, buf2);
  gemm_dual<<<gblocks, 256, 0, stream>>>(buf2, dscr, Wl1, Wr1, D, bl1, buf1, NN);      // h
  gemm_dual<<<gblocks, 256, 0, stream>>>(dscr, buf1, Wc, Wc + D, 2 * D, bc, buf2, NN); // x2

  // ---- edge classifier -----------------------------------------------------
  edge_k<<<1024, 256, 0, stream>>>(buf2, src, dst, Wo, bo, flags, d_out, NE);
}

// Round 7
// 554.110 us; speedup vs baseline: 3.6872x; 1.0812x over previous
//
#include <hip/hip_runtime.h>
#include <hip/hip_bf16.h>

#define NN 100000      // nodes
#define NE 1000000     // edges
#define D  128         // hidden / input dim
#define NC 16          // classes

typedef short short8 __attribute__((ext_vector_type(8)));
typedef float f32x4  __attribute__((ext_vector_type(4)));

__device__ __forceinline__ float bf2f(ushort u) {
  union { unsigned int i; float f; } v; v.i = ((unsigned int)u) << 16; return v.f;
}
__device__ __forceinline__ ushort f2bf(float f) {
  union { float f; unsigned int i; } v; v.f = f;
  unsigned int x = v.i;
  return (ushort)((x + 0x7FFFu + ((x >> 16) & 1u)) >> 16);  // RNE
}

// ---- sniff dtypes: flags[0]=1 if float tensors are f32; flags[1]=1 if idx int64
__global__ void sniff_k(const ushort* __restrict__ xr, const unsigned int* __restrict__ ei,
                        int* __restrict__ flags) {
  if (threadIdx.x != 0 || blockIdx.x != 0) return;
  int f32 = 0;
  for (int i = 0; i < 128; ++i) {
    unsigned int e = ((unsigned int)xr[i] >> 7) & 0xFFu;
    if (e < 97u || e > 157u) f32 = 1;
  }
  flags[0] = f32;
  unsigned int s = 0;
  for (int i = 1; i < 256; i += 2) s |= ei[i];   // int64 < 2^31 => hi words all 0
  flags[1] = (s == 0) ? 1 : 0;
}

// ---- materialize clean int32 indices, clamped to [0,NN) ---------------------
__global__ void convert_idx_k(const int* __restrict__ ei, const int* __restrict__ flags,
                              int* __restrict__ idx, int n) {
  int i = blockIdx.x * blockDim.x + threadIdx.x;
  if (i >= n) return;
  int v = flags[1] ? ei[2 * i] : ei[i];   // int64: take low word
  v = v < 0 ? 0 : (v >= NN ? NN - 1 : v);
  idx[i] = v;
}

// ---- convert x to canonical bf16 -------------------------------------------
__global__ void convert_x_k(const void* __restrict__ xin, const int* __restrict__ flags,
                            ushort* __restrict__ xb) {
  int i = blockIdx.x * blockDim.x + threadIdx.x;
  const int n4 = NN * D / 4;
  if (i >= n4) return;
  ushort4 o;
  if (flags[0]) {
    float4 v = ((const float4*)xin)[i];
    o.x = f2bf(v.x); o.y = f2bf(v.y); o.z = f2bf(v.z); o.w = f2bf(v.w);
  } else {
    o = ((const ushort4*)xin)[i];
  }
  ((ushort4*)xb)[i] = o;
}

// ---- convert all weights/biases to canonical bf16 block --------------------
struct WPtrs { const void* p[10]; };
#define WTOT 102800
__global__ void convert_w_k(WPtrs w, const int* __restrict__ flags, ushort* __restrict__ wb) {
  const int off[10] = {0, 16384, 32768, 49152, 65536, 98304, 102400, 102528, 102656, 102784};
  int i = blockIdx.x * blockDim.x + threadIdx.x;
  if (i >= WTOT) return;
  int seg = 0;
  #pragma unroll
  for (int s2 = 1; s2 < 10; ++s2) if (i >= off[s2]) seg = s2;
  int j = i - off[seg];
  wb[i] = flags[0] ? f2bf(((const float*)w.p[seg])[j]) : ((const ushort*)w.p[seg])[j];
}

// ---- degree count -----------------------------------------------------------
__global__ void count_k(const int* __restrict__ dst, int* __restrict__ cnt, int E) {
  int e = blockIdx.x * blockDim.x + threadIdx.x;
  if (e < E) atomicAdd(&cnt[dst[e]], 1);
}

// ---- hierarchical exclusive scan: cnt[NN] -> off[NN+1], cur[NN] -------------
#define NCHUNK ((NN + 255) / 256)   // 391
__global__ void scan1_k(const int* __restrict__ cnt, int* __restrict__ csum) {
  __shared__ int tmp[256];
  int i = blockIdx.x * 256 + threadIdx.x;
  tmp[threadIdx.x] = (i < NN) ? cnt[i] : 0;
  __syncthreads();
  #pragma unroll
  for (int s = 128; s > 0; s >>= 1) {
    if (threadIdx.x < s) tmp[threadIdx.x] += tmp[threadIdx.x + s];
    __syncthreads();
  }
  if (threadIdx.x == 0) csum[blockIdx.x] = tmp[0];
}
__global__ void scan2_k(int* __restrict__ csum) {   // 1 block, 512 thr, n=NCHUNK
  __shared__ int tmp[512];
  int t = threadIdx.x;
  int self = (t < NCHUNK) ? csum[t] : 0;
  tmp[t] = self;
  __syncthreads();
  for (int s = 1; s < 512; s <<= 1) {
    int v = (t >= s) ? tmp[t - s] : 0;
    __syncthreads();
    tmp[t] += v;
    __syncthreads();
  }
  if (t < NCHUNK) csum[t] = tmp[t] - self;   // exclusive
}
__global__ void scan3_k(const int* __restrict__ cnt, const int* __restrict__ csum,
                        int* __restrict__ off, int* __restrict__ cur) {
  __shared__ int tmp[256];
  int i = blockIdx.x * 256 + threadIdx.x;
  int t = threadIdx.x;
  int self = (i < NN) ? cnt[i] : 0;
  tmp[t] = self;
  __syncthreads();
  for (int s = 1; s < 256; s <<= 1) {
    int v = (t >= s) ? tmp[t - s] : 0;
    __syncthreads();
    tmp[t] += v;
    __syncthreads();
  }
  int excl = csum[blockIdx.x] + tmp[t] - self;
  if (i < NN) { off[i] = excl; cur[i] = excl; }
  if (i == NN - 1) off[NN] = excl + self;
}

// ---- bucket: nbr[] = src ids grouped by dst (CSR) ---------------------------
__global__ void bucket_k(const int* __restrict__ src, const int* __restrict__ dst,
                         int* __restrict__ cur, int* __restrict__ nbr, int E) {
  int e = blockIdx.x * blockDim.x + threadIdx.x;
  if (e >= E) return;
  int pos = atomicAdd(&cur[dst[e]], 1);
  nbr[pos] = src[e];
}

// ---- segmented mean: one wave per node, 64 lanes x 2 f32 acc = 128 dims -----
__global__ __launch_bounds__(256) void agg_k(
    const ushort* __restrict__ X, const int* __restrict__ nbr,
    const int* __restrict__ off, ushort* __restrict__ mean) {
  const int wave = threadIdx.x >> 6, lane = threadIdx.x & 63;
  const int node = blockIdx.x * 4 + wave;
  if (node >= NN) return;
  const int j0 = off[node], j1 = off[node + 1];
  float a0 = 0.f, a1 = 0.f;
  int j = j0;
  for (; j + 1 < j1; j += 2) {    // 2 edges/iter for load ILP
    int s0 = nbr[j], s1 = nbr[j + 1];
    unsigned int v0 = *(const unsigned int*)(X + (size_t)s0 * D + lane * 2);
    unsigned int v1 = *(const unsigned int*)(X + (size_t)s1 * D + lane * 2);
    a0 += bf2f((ushort)(v0 & 0xffffu)) + bf2f((ushort)(v1 & 0xffffu));
    a1 += bf2f((ushort)(v0 >> 16))     + bf2f((ushort)(v1 >> 16));
  }
  if (j < j1) {
    unsigned int v0 = *(const unsigned int*)(X + (size_t)nbr[j] * D + lane * 2);
    a0 += bf2f((ushort)(v0 & 0xffffu));
    a1 += bf2f((ushort)(v0 >> 16));
  }
  int deg = j1 - j0;
  float inv = 1.f / (float)(deg > 1 ? deg : 1);
  unsigned int o = (unsigned int)f2bf(a0 * inv) | ((unsigned int)f2bf(a1 * inv) << 16);
  *(unsigned int*)(mean + (size_t)node * D + lane * 2) = o;
}

// ---- Y = relu(A1@W1^T + A2@W2^T + bias), all [.,128] -----------------------
__global__ __launch_bounds__(256) void gemm_dual(
    const ushort* __restrict__ A1, const ushort* __restrict__ A2,
    const ushort* __restrict__ W1, const ushort* __restrict__ W2, int ldw,
    const ushort* __restrict__ bias, ushort* __restrict__ Y, int nrows)
{
  __shared__ ushort wlds[32 * 64 * 8];   // 32 KiB
  const int tid = threadIdx.x;
  const int wave = tid >> 6, lane = tid & 63;
  const int l15 = lane & 15, q = lane >> 4;
  const int m0 = blockIdx.x * 128 + wave * 32;

  f32x4 acc[2][8];
  #pragma unroll
  for (int rt = 0; rt < 2; ++rt)
    #pragma unroll
    for (int c = 0; c < 8; ++c) acc[rt][c] = (f32x4){0.f, 0.f, 0.f, 0.f};

  for (int phase = 0; phase < 2; ++phase) {
    const ushort* W = phase ? W2 : W1;
    const ushort* A = phase ? A2 : A1;
    __syncthreads();
    #pragma unroll
    for (int it = 0; it < 8; ++it) {
      int combo = it * 4 + wave;         // c = combo>>2, ks = combo&3
      int c = combo >> 2, ks = combo & 3;
      *(uint4*)(&wlds[(combo * 64 + lane) * 8]) =
          *(const uint4*)(W + (size_t)(c * 16 + l15) * ldw + ks * 32 + q * 8);
    }
    __syncthreads();
    #pragma unroll
    for (int ks = 0; ks < 4; ++ks) {
      short8 af[2];
      #pragma unroll
      for (int rt = 0; rt < 2; ++rt) {
        int row = m0 + rt * 16 + l15;
        if (row > nrows - 1) row = nrows - 1;   // clamp (stores are guarded)
        af[rt] = *(const short8*)(A + (size_t)row * D + ks * 32 + q * 8);
      }
      #pragma unroll
      for (int c = 0; c < 8; ++c) {
        short8 bf = *(const short8*)(&wlds[((c * 4 + ks) * 64 + lane) * 8]);
        acc[0][c] = __builtin_amdgcn_mfma_f32_16x16x32_bf16(af[0], bf, acc[0][c], 0, 0, 0);
        acc[1][c] = __builtin_amdgcn_mfma_f32_16x16x32_bf16(af[1], bf, acc[1][c], 0, 0, 0);
      }
    }
  }
  // C/D layout: col = lane&15, row = (lane>>4)*4 + r   [m89-verified]
  #pragma unroll
  for (int c = 0; c < 8; ++c) {
    float b = bf2f(bias[c * 16 + l15]);
    #pragma unroll
    for (int rt = 0; rt < 2; ++rt) {
      #pragma unroll
      for (int r = 0; r < 4; ++r) {
        int row = m0 + rt * 16 + q * 4 + r;
        if (row < nrows) {
          float v = acc[rt][c][r] + b;
          v = v > 0.f ? v : 0.f;
          Y[(size_t)row * D + c * 16 + l15] = f2bf(v);
        }
      }
    }
  }
}

// ---- P[node, 0:16] = x2[node] @ Wo[:, 0:128]^T ; P[node,16:32] = @ Wo[:,128:]^T
// one wave = 16 rows x 32 cols, K=128; f32 output (exact edge sums later)
__global__ __launch_bounds__(256) void gemm_po(
    const ushort* __restrict__ X2, const ushort* __restrict__ Wo, float* __restrict__ P)
{
  __shared__ ushort wlds[8 * 64 * 8];    // 8 KiB: combo = c*4+ks
  const int tid = threadIdx.x, wave = tid >> 6, lane = tid & 63;
  const int l15 = lane & 15, q = lane >> 4;
  const int m0 = blockIdx.x * 64 + wave * 16;
  #pragma unroll
  for (int it = 0; it < 2; ++it) {
    int combo = it * 4 + wave;           // c = combo>>2 (col half), ks = combo&3
    int c = combo >> 2, ks = combo & 3;
    *(uint4*)(&wlds[(combo * 64 + lane) * 8]) =
        *(const uint4*)(Wo + (size_t)l15 * 256 + c * 128 + ks * 32 + q * 8);
  }
  __syncthreads();
  f32x4 acc[2] = {(f32x4){0.f,0.f,0.f,0.f}, (f32x4){0.f,0.f,0.f,0.f}};
  #pragma unroll
  for (int ks = 0; ks < 4; ++ks) {
    int row = m0 + l15; if (row > NN - 1) row = NN - 1;
    short8 af = *(const short8*)(X2 + (size_t)row * D + ks * 32 + q * 8);
    #pragma unroll
    for (int c = 0; c < 2; ++c) {
      short8 bf = *(const short8*)(&wlds[((c * 4 + ks) * 64 + lane) * 8]);
      acc[c] = __builtin_amdgcn_mfma_f32_16x16x32_bf16(af, bf, acc[c], 0, 0, 0);
    }
  }
  #pragma unroll
  for (int c = 0; c < 2; ++c)
    #pragma unroll
    for (int r = 0; r < 4; ++r) {
      int row = m0 + q * 4 + r;
      if (row < NN) P[(size_t)row * 32 + c * 16 + l15] = acc[c][r];
    }
}

// ---- out[e,c] = P[src[e]][c] + P[dst[e]][16+c] + bo[c] ---------------------
__global__ __launch_bounds__(256) void edge_sum_k(
    const float* __restrict__ P, const int* __restrict__ src, const int* __restrict__ dst,
    const ushort* __restrict__ bo, const int* __restrict__ flags,
    void* __restrict__ outv, int E)
{
  int gid = blockIdx.x * blockDim.x + threadIdx.x;
  if (gid >= E * 4) return;
  int e = gid >> 2, cq = (gid & 3) * 4;
  int s = src[e], d = dst[e];
  float4 a = *(const float4*)(P + (size_t)s * 32 + cq);
  float4 b = *(const float4*)(P + (size_t)d * 32 + 16 + cq);
  float4 o;
  o.x = a.x + b.x + bf2f(bo[cq + 0]);
  o.y = a.y + b.y + bf2f(bo[cq + 1]);
  o.z = a.z + b.z + bf2f(bo[cq + 2]);
  o.w = a.w + b.w + bf2f(bo[cq + 3]);
  if (flags[0]) {
    ((float4*)outv)[gid] = o;
  } else {
    ushort4 u;
    u.x = f2bf(o.x); u.y = f2bf(o.y); u.z = f2bf(o.z); u.w = f2bf(o.w);
    ((ushort4*)outv)[gid] = u;
  }
}

extern "C" void kernel_launch(void* const* d_in, const int* in_sizes, int n_in,
                              void* d_out, int out_size, void* d_ws, size_t ws_size,
                              hipStream_t stream) {
  const void* x_in = d_in[0];
  const int*  ei   = (const int*)d_in[1];

  // workspace layout (bytes): total ~64.6 MB
  char* ws = (char*)d_ws;
  int*    idx   = (int*)(ws + 0);              //  8,000,000 (src | dst)
  int*    cnt   = (int*)(ws + 8000000);        //    400,000
  int*    flags = (int*)(ws + 8400000);        //        256
  ushort* wb    = (ushort*)(ws + 8400256);     //    205,600
  int*    off   = (int*)(ws + 8605856);        //    400,004
  int*    cur   = (int*)(ws + 9005872);        //    400,000
  int*    nbr   = (int*)(ws + 9405872);        //  4,000,000
  int*    csum  = (int*)(ws + 13405872);       //      1,564 (NCHUNK ints)
  ushort* buf1  = (ushort*)(ws + 13407440);    // 25,600,000 (h; later P as f32 12.8MB)
  ushort* buf2  = (ushort*)(ws + 39007440);    // 25,600,000 (xb / meanL1 / x2)
  ushort* dscr  = (ushort*)d_out;              // d_out scratch: meanL0 / x1
  float*  P     = (float*)buf1;                // alias: buf1 dead after last gemm_dual

  int* src = idx;
  int* dst = idx + NE;

  ushort* Wl0 = wb + 0,      *Wr0 = wb + 16384, *Wl1 = wb + 32768, *Wr1 = wb + 49152;
  ushort* Wc  = wb + 65536,  *Wo  = wb + 98304;
  ushort* bl0 = wb + 102400, *bl1 = wb + 102528, *bc = wb + 102656, *bo = wb + 102784;

  WPtrs w;
  w.p[0] = d_in[2];  w.p[1] = d_in[4];  w.p[2] = d_in[5];  w.p[3] = d_in[7];
  w.p[4] = d_in[8];  w.p[5] = d_in[10]; w.p[6] = d_in[3];  w.p[7] = d_in[6];
  w.p[8] = d_in[9];  w.p[9] = d_in[11];

  const int gblocks = (NN + 127) / 128;        // 782
  const int n4 = NN * D / 4;
  const int agrid = (NN + 3) / 4;              // 25,000 (4 nodes/block)

  sniff_k<<<1, 64, 0, stream>>>((const ushort*)x_in, (const unsigned int*)ei, flags);
  convert_idx_k<<<(2 * NE + 255) / 256, 256, 0, stream>>>(ei, flags, idx, 2 * NE);
  convert_x_k<<<(n4 + 255) / 256, 256, 0, stream>>>(x_in, flags, buf2);
  convert_w_k<<<(WTOT + 255) / 256, 256, 0, stream>>>(w, flags, wb);

  // ---- build CSR (dst-grouped src list) — once, reused by both layers ------
  (void)hipMemsetAsync(cnt, 0, NN * sizeof(int), stream);
  count_k<<<(NE + 255) / 256, 256, 0, stream>>>(dst, cnt, NE);
  scan1_k<<<NCHUNK, 256, 0, stream>>>(cnt, csum);
  scan2_k<<<1, 512, 0, stream>>>(csum);
  scan3_k<<<NCHUNK, 256, 0, stream>>>(cnt, csum, off, cur);
  bucket_k<<<(NE + 255) / 256, 256, 0, stream>>>(src, dst, cur, nbr, NE);

  // ---- layer 0: x=buf2 -> mean=dscr -> h=buf1 -> x1=dscr -------------------
  agg_k<<<agrid, 256, 0, stream>>>(buf2, nbr, off, dscr);
  gemm_dual<<<gblocks, 256, 0, stream>>>(dscr, buf2, Wl0, Wr0, D, bl0, buf1, NN);      // h
  gemm_dual<<<gblocks, 256, 0, stream>>>(buf2, buf1, Wc, Wc + D, 2 * D, bc, dscr, NN); // x1

  // ---- layer 1: x1=dscr -> mean=buf2 -> h=buf1 -> x2=buf2 ------------------
  agg_k<<<agrid, 256, 0, stream>>>(dscr, nbr, off, buf2);
  gemm_dual<<<gblocks, 256, 0, stream>>>(buf2, dscr, Wl1, Wr1, D, bl1, buf1, NN);      // h
  gemm_dual<<<gblocks, 256, 0, stream>>>(dscr, buf1, Wc, Wc + D, 2 * D, bc, buf2, NN); // x2

  // ---- edge classifier: factored P-GEMM + gather-sum -----------------------
  gemm_po<<<(NN + 63) / 64, 256, 0, stream>>>(buf2, Wo, P);
  edge_sum_k<<<(4 * NE + 255) / 256, 256, 0, stream>>>(P, src, dst, bo, flags, d_out, NE);
}